// Round 1
// baseline (1407.268 us; speedup 1.0000x reference)
//
#include <hip/hip_runtime.h>

// Problem constants (from reference): N_NODES=50000, N_EDGES=800000,
// N_GRAPHS=64, IN_CH=HID=64. We derive n-nodes / n-edges / n-graphs from
// in_sizes/out_size so shapes aren't hard-coded.

__global__ void deg_count_k(const int* __restrict__ dst, int nE, int* __restrict__ cnt) {
    int i = blockIdx.x * blockDim.x + threadIdx.x;
    if (i < nE) atomicAdd(&cnt[dst[i]], 1);
}

__global__ void dinv_k(const int* __restrict__ cnt, int n, float* __restrict__ dinv) {
    int i = blockIdx.x * blockDim.x + threadIdx.x;
    if (i < n) dinv[i] = 1.0f / sqrtf(1.0f + (float)cnt[i]);
}

// out[row][c] = sum_k X[row][k] * W[k][c]   (64x64 W staged in LDS)
// One wave (64 lanes) per row; x-row loaded coalesced once, broadcast via shfl.
template <int DUAL>
__global__ __launch_bounds__(256) void mm64_k(
    const float* __restrict__ X,
    const float* __restrict__ Wa, const float* __restrict__ Wb,
    float* __restrict__ Oa, float* __restrict__ Ob, int n) {
    __shared__ float wa[64][64];
    __shared__ float wb[64][64];
    for (int i = threadIdx.x; i < 64 * 64; i += blockDim.x) {
        wa[i >> 6][i & 63] = Wa[i];
        if (DUAL) wb[i >> 6][i & 63] = Wb[i];
    }
    __syncthreads();
    const int lane = threadIdx.x & 63;
    const int wpb = blockDim.x >> 6;
    const int row0 = blockIdx.x * wpb + (threadIdx.x >> 6);
    const int stride = gridDim.x * wpb;
    for (int row = row0; row < n; row += stride) {
        float xv = X[row * 64 + lane];
        float acc1 = 0.f, acc2 = 0.f;
#pragma unroll
        for (int k = 0; k < 64; ++k) {
            float xb = __shfl(xv, k);
            acc1 = fmaf(xb, wa[k][lane], acc1);
            if (DUAL) acc2 = fmaf(xb, wb[k][lane], acc2);
        }
        Oa[row * 64 + lane] = acc1;
        if (DUAL) Ob[row * 64 + lane] = acc2;
    }
}

// agg[dst] += dinv[src]*dinv[dst] * H[src]   (one wave per edge, 64 channels)
__global__ __launch_bounds__(256) void scatter_k(
    const int* __restrict__ src, const int* __restrict__ dst,
    const float* __restrict__ dinv, const float* __restrict__ H,
    float* __restrict__ agg, int nE) {
    int e = blockIdx.x * (blockDim.x >> 6) + (threadIdx.x >> 6);
    int lane = threadIdx.x & 63;
    if (e < nE) {
        int s = src[e];
        int d = dst[e];
        float w = dinv[s] * dinv[d];
        atomicAdd(&agg[d * 64 + lane], w * H[s * 64 + lane]);
    }
}

// MODE 0: out = relu(agg + sn*hw + b) + relu(skip + bskip)     (layer 1)
// MODE 1: out = relu(agg + sn*hw + b) + skip                   (layer 2 residual)
template <int MODE>
__global__ __launch_bounds__(256) void combine_k(
    const float* __restrict__ agg, const float* __restrict__ hw,
    const float* __restrict__ b, const float* __restrict__ skip,
    const float* __restrict__ bskip, const float* __restrict__ dinv,
    float* __restrict__ out, int n) {
    int i = blockIdx.x * blockDim.x + threadIdx.x;
    if (i < n * 64) {
        int node = i >> 6;
        int ch = i & 63;
        float sn = dinv[node];
        sn *= sn;
        float v = agg[i] + sn * hw[i] + b[ch];
        v = fmaxf(v, 0.0f);
        if (MODE == 0) {
            float s2 = skip[i] + bskip[ch];
            v += fmaxf(s2, 0.0f);
        } else {
            v += skip[i];
        }
        out[i] = v;
    }
}

// sums[batch[node]] += h2[node]+hs2[node];  cnts[batch[node]] += 1
__global__ __launch_bounds__(256) void pool_k(
    const float* __restrict__ h2, const float* __restrict__ hs2,
    const int* __restrict__ batch, float* __restrict__ sums,
    float* __restrict__ cnts, int n) {
    int node = blockIdx.x * (blockDim.x >> 6) + (threadIdx.x >> 6);
    int lane = threadIdx.x & 63;
    if (node < n) {
        int g = batch[node];
        atomicAdd(&sums[g * 64 + lane], h2[node * 64 + lane] + hs2[node * 64 + lane]);
        if (lane == 0) atomicAdd(&cnts[g], 1.0f);
    }
}

// out[g] = dot(sums[g]/max(cnt[g],1), Wf) + bf
__global__ void final_k(const float* __restrict__ sums, const float* __restrict__ cnts,
                        const float* __restrict__ Wf, const float* __restrict__ bf,
                        float* __restrict__ out, int ngraphs) {
    int g = blockIdx.x * blockDim.x + threadIdx.x;
    if (g < ngraphs) {
        float c = fmaxf(cnts[g], 1.0f);
        float acc = 0.f;
        for (int k = 0; k < 64; ++k) acc += sums[g * 64 + k] * Wf[k];
        out[g] = acc / c + bf[0];
    }
}

extern "C" void kernel_launch(void* const* d_in, const int* in_sizes, int n_in,
                              void* d_out, int out_size, void* d_ws, size_t ws_size,
                              hipStream_t stream) {
    const float* x    = (const float*)d_in[0];
    const float* x_SC = (const float*)d_in[1];
    const float* W1   = (const float*)d_in[2];
    const float* b1   = (const float*)d_in[3];
    const float* W2   = (const float*)d_in[4];
    const float* b2   = (const float*)d_in[5];
    const float* We   = (const float*)d_in[6];
    const float* be   = (const float*)d_in[7];
    const float* W1s  = (const float*)d_in[8];
    const float* b1s  = (const float*)d_in[9];
    const float* W2s  = (const float*)d_in[10];
    const float* b2s  = (const float*)d_in[11];
    const float* Wes  = (const float*)d_in[12];
    const float* bes  = (const float*)d_in[13];
    const float* Wf   = (const float*)d_in[14];
    const float* bf   = (const float*)d_in[15];
    const int* ei     = (const int*)d_in[16];
    const int* batch  = (const int*)d_in[17];

    const int nN = in_sizes[0] / 64;           // 50000
    const int nE = in_sizes[16] / 2;           // 800000
    const int nG = out_size;                   // 64 (pooled @ Wf -> [G,1])
    const int* esrc = ei;
    const int* edst = ei + nE;

    // Workspace layout (floats / ints, all 4B-aligned)
    float* w = (float*)d_ws;
    int*   cnt  = (int*)w;          w += nN;
    float* dinv = w;                w += nN;
    float* A    = w;                w += (size_t)nN * 64;   // matmul out / hw
    float* B    = w;                w += (size_t)nN * 64;   // skip-matmul out, later HS2
    float* C    = w;                w += (size_t)nN * 64;   // scatter agg
    float* H1   = w;                w += (size_t)nN * 64;   // layer-1 out (both branches)
    float* H2   = w;                w += (size_t)nN * 64;   // branch-1 final
    float* sums = w;                w += (size_t)nG * 64;
    float* cnts = w;                w += nG;

    const size_t featB = (size_t)nN * 64 * sizeof(float);
    const int thr = 256;
    const int gElem = (nN * 64 + thr - 1) / thr;       // elementwise grid
    const int gEdge = (nE + 3) / 4;                    // 4 waves/block, 1 wave/edge
    const int gNode = (nN + 3) / 4;

    // ---- degrees ----
    hipMemsetAsync(cnt, 0, nN * sizeof(int), stream);
    deg_count_k<<<(nE + thr - 1) / thr, thr, 0, stream>>>(edst, nE, cnt);
    dinv_k<<<(nN + thr - 1) / thr, thr, 0, stream>>>(cnt, nN, dinv);

    // ---- branch 1, layer 1 ----
    mm64_k<1><<<1024, thr, 0, stream>>>(x, W1, We, A, B, nN);
    hipMemsetAsync(C, 0, featB, stream);
    scatter_k<<<gEdge, thr, 0, stream>>>(esrc, edst, dinv, A, C, nE);
    combine_k<0><<<gElem, thr, 0, stream>>>(C, A, b1, B, be, dinv, H1, nN);

    // ---- branch 1, layer 2 ----
    mm64_k<0><<<1024, thr, 0, stream>>>(H1, W2, nullptr, A, nullptr, nN);
    hipMemsetAsync(C, 0, featB, stream);
    scatter_k<<<gEdge, thr, 0, stream>>>(esrc, edst, dinv, A, C, nE);
    combine_k<1><<<gElem, thr, 0, stream>>>(C, A, b2, H1, nullptr, dinv, H2, nN);

    // ---- branch 2 (x_SC), layer 1 ----
    mm64_k<1><<<1024, thr, 0, stream>>>(x_SC, W1s, Wes, A, B, nN);
    hipMemsetAsync(C, 0, featB, stream);
    scatter_k<<<gEdge, thr, 0, stream>>>(esrc, edst, dinv, A, C, nE);
    combine_k<0><<<gElem, thr, 0, stream>>>(C, A, b1s, B, bes, dinv, H1, nN);

    // ---- branch 2, layer 2 (HS2 -> B) ----
    mm64_k<0><<<1024, thr, 0, stream>>>(H1, W2s, nullptr, A, nullptr, nN);
    hipMemsetAsync(C, 0, featB, stream);
    scatter_k<<<gEdge, thr, 0, stream>>>(esrc, edst, dinv, A, C, nE);
    combine_k<1><<<gElem, thr, 0, stream>>>(C, A, b2s, H1, nullptr, dinv, B, nN);

    // ---- pooling + final projection ----
    hipMemsetAsync(sums, 0, (size_t)(nG * 64 + nG) * sizeof(float), stream);
    pool_k<<<gNode, thr, 0, stream>>>(H2, B, batch, sums, cnts, nN);
    final_k<<<1, 64, 0, stream>>>(sums, cnts, Wf, bf, (float*)d_out, nG);
}

// Round 2
// 733.634 us; speedup vs baseline: 1.9182x; 1.9182x over previous
//
#include <hip/hip_runtime.h>

// GCN x2 layers x2 branches on N=50000 nodes, E=800000 edges, C=64 channels.
// Strategy: dst-CSR built per-launch; aggregation is a register-accumulating
// gather (no f32 atomics); norm folded by pre-scaling h with dinv in the
// matmul epilogue; combine fused into the gather kernel; pool+final fused,
// atomic-free (batch is sorted).

// ---- degree histogram (also used as CSR fill cursor) ----
__global__ void deg_count_k(const int* __restrict__ dst, int nE, int* __restrict__ cnt) {
    int i = blockIdx.x * blockDim.x + threadIdx.x;
    if (i < nE) atomicAdd(&cnt[dst[i]], 1);
}

__global__ void dinv_k(const int* __restrict__ cnt, int n, float* __restrict__ dinv) {
    int i = blockIdx.x * blockDim.x + threadIdx.x;
    if (i < n) dinv[i] = 1.0f / sqrtf(1.0f + (float)cnt[i]);
}

// Single-block exclusive scan of cnt[0..n) -> offs[0..n], offs[n] = total.
__global__ __launch_bounds__(1024) void scan_k(const int* __restrict__ cnt, int n,
                                               int* __restrict__ offs) {
    __shared__ int buf[1024];
    __shared__ int carry;
    if (threadIdx.x == 0) carry = 0;
    __syncthreads();
    for (int base = 0; base < n; base += 1024) {
        int i = base + threadIdx.x;
        int v = (i < n) ? cnt[i] : 0;
        buf[threadIdx.x] = v;
        __syncthreads();
#pragma unroll
        for (int off = 1; off < 1024; off <<= 1) {
            int t = (threadIdx.x >= off) ? buf[threadIdx.x - off] : 0;
            __syncthreads();
            buf[threadIdx.x] += t;
            __syncthreads();
        }
        if (i < n) offs[i] = carry + buf[threadIdx.x] - v;  // exclusive
        int total = buf[1023];
        __syncthreads();
        if (threadIdx.x == 0) carry += total;
        __syncthreads();
    }
    if (threadIdx.x == 0) offs[n] = carry;
}

// Scatter edges into CSR buckets: elist[pos] = src, pos = cur[dst]++.
__global__ void fill_k(const int* __restrict__ src, const int* __restrict__ dst, int nE,
                       int* __restrict__ cur, int* __restrict__ elist) {
    int e = blockIdx.x * blockDim.x + threadIdx.x;
    if (e < nE) {
        int d = dst[e];
        int p = atomicAdd(&cur[d], 1);
        elist[p] = src[e];
    }
}

// Oa[row] = scale(row) * (X[row] @ Wa); Ob[row] = X[row] @ Wb (unscaled skip path)
// One wave per row, W staged in LDS, x-row broadcast via shfl.
template <int DUAL>
__global__ __launch_bounds__(256) void mm64_k(
    const float* __restrict__ X,
    const float* __restrict__ Wa, const float* __restrict__ Wb,
    const float* __restrict__ dinv,
    float* __restrict__ Oa, float* __restrict__ Ob, int n) {
    __shared__ float wa[64][64];
    __shared__ float wb[64][64];
    for (int i = threadIdx.x; i < 64 * 64; i += blockDim.x) {
        wa[i >> 6][i & 63] = Wa[i];
        if (DUAL) wb[i >> 6][i & 63] = Wb[i];
    }
    __syncthreads();
    const int lane = threadIdx.x & 63;
    const int wpb = blockDim.x >> 6;
    const int row0 = blockIdx.x * wpb + (threadIdx.x >> 6);
    const int stride = gridDim.x * wpb;
    for (int row = row0; row < n; row += stride) {
        float xv = X[row * 64 + lane];
        float acc1 = 0.f, acc2 = 0.f;
#pragma unroll
        for (int k = 0; k < 64; ++k) {
            float xb = __shfl(xv, k);
            acc1 = fmaf(xb, wa[k][lane], acc1);
            if (DUAL) acc2 = fmaf(xb, wb[k][lane], acc2);
        }
        Oa[row * 64 + lane] = dinv[row] * acc1;
        if (DUAL) Ob[row * 64 + lane] = acc2;
    }
}

// Fused aggregate + combine. A is dinv-prescaled (A[r] = dinv[r] * h[r]).
//   gcn[d] = dinv[d] * (sum_{e in CSR[d]} A[src] + A[d]) + b
// MODE 0: out = relu(gcn) + relu(skip + bskip)    (layer 1; skip = X@We)
// MODE 1: out = relu(gcn) + skip                   (layer 2 residual; skip = H1)
template <int MODE>
__global__ __launch_bounds__(256) void agg_combine_k(
    const int* __restrict__ offs, const int* __restrict__ elist,
    const float* __restrict__ A, const float* __restrict__ b,
    const float* __restrict__ skip, const float* __restrict__ bskip,
    const float* __restrict__ dinv,
    float* __restrict__ out, int n) {
    int node = blockIdx.x * (blockDim.x >> 6) + (threadIdx.x >> 6);
    int lane = threadIdx.x & 63;
    if (node >= n) return;
    int e0 = offs[node], e1 = offs[node + 1];
    float acc = A[node * 64 + lane];  // self-loop term (dinv^2 * h folds as dinv*A)
    int e = e0;
    for (; e + 1 < e1; e += 2) {  // 2-way unroll for memory-level parallelism
        int s0 = elist[e], s1 = elist[e + 1];
        float v0 = A[s0 * 64 + lane];
        float v1 = A[s1 * 64 + lane];
        acc += v0 + v1;
    }
    if (e < e1) acc += A[elist[e] * 64 + lane];
    float v = fmaxf(dinv[node] * acc + b[lane], 0.0f);
    if (MODE == 0) {
        v += fmaxf(skip[node * 64 + lane] + bskip[lane], 0.0f);
    } else {
        v += skip[node * 64 + lane];
    }
    out[node * 64 + lane] = v;
}

// One block per graph; batch is sorted so each graph is a contiguous range.
// out[g] = dot(mean_{node in g}(h2+hs2), Wf) + bf  — fully atomic-free.
__device__ inline int lower_bound(const int* __restrict__ batch, int n, int g) {
    int lo = 0, hi = n;
    while (lo < hi) {
        int mid = (lo + hi) >> 1;
        if (batch[mid] < g) lo = mid + 1; else hi = mid;
    }
    return lo;
}

__global__ __launch_bounds__(256) void pool_final_k(
    const float* __restrict__ h2, const float* __restrict__ hs2,
    const int* __restrict__ batch, int n,
    const float* __restrict__ Wf, const float* __restrict__ bf,
    float* __restrict__ out) {
    int g = blockIdx.x;
    int start = lower_bound(batch, n, g);
    int end = lower_bound(batch, n, g + 1);
    int lane = threadIdx.x & 63, wid = threadIdx.x >> 6;
    __shared__ float part[4][64];
    float acc = 0.f;
    for (int node = start + wid; node < end; node += 4)
        acc += h2[node * 64 + lane] + hs2[node * 64 + lane];
    part[wid][lane] = acc;
    __syncthreads();
    if (wid == 0) {
        float s = part[0][lane] + part[1][lane] + part[2][lane] + part[3][lane];
        float cnt = fmaxf((float)(end - start), 1.0f);
        s = (s / cnt) * Wf[lane];
#pragma unroll
        for (int off = 32; off > 0; off >>= 1) s += __shfl_down(s, off);
        if (lane == 0) out[g] = s + bf[0];
    }
}

extern "C" void kernel_launch(void* const* d_in, const int* in_sizes, int n_in,
                              void* d_out, int out_size, void* d_ws, size_t ws_size,
                              hipStream_t stream) {
    const float* x    = (const float*)d_in[0];
    const float* x_SC = (const float*)d_in[1];
    const float* W1   = (const float*)d_in[2];
    const float* b1   = (const float*)d_in[3];
    const float* W2   = (const float*)d_in[4];
    const float* b2   = (const float*)d_in[5];
    const float* We   = (const float*)d_in[6];
    const float* be   = (const float*)d_in[7];
    const float* W1s  = (const float*)d_in[8];
    const float* b1s  = (const float*)d_in[9];
    const float* W2s  = (const float*)d_in[10];
    const float* b2s  = (const float*)d_in[11];
    const float* Wes  = (const float*)d_in[12];
    const float* bes  = (const float*)d_in[13];
    const float* Wf   = (const float*)d_in[14];
    const float* bf   = (const float*)d_in[15];
    const int* ei     = (const int*)d_in[16];
    const int* batch  = (const int*)d_in[17];

    const int nN = in_sizes[0] / 64;   // 50000
    const int nE = in_sizes[16] / 2;   // 800000
    const int nG = out_size;           // 64
    const int* esrc = ei;
    const int* edst = ei + nE;

    // ---- workspace layout ----
    char* p = (char*)d_ws;
    int* cur   = (int*)p;   p += (size_t)nN * sizeof(int);
    int* offs  = (int*)p;   p += (size_t)(nN + 1) * sizeof(int);
    int* elist = (int*)p;   p += (size_t)nE * sizeof(int);
    float* dinv = (float*)p; p += (size_t)nN * sizeof(float);
    float* A   = (float*)p; p += (size_t)nN * 64 * sizeof(float);
    float* B   = (float*)p; p += (size_t)nN * 64 * sizeof(float);
    float* H1  = (float*)p; p += (size_t)nN * 64 * sizeof(float);
    float* H2  = (float*)p; p += (size_t)nN * 64 * sizeof(float);

    const int thr = 256;
    const int gEdgeT = (nE + thr - 1) / thr;
    const int gNodeT = (nN + thr - 1) / thr;
    const int gNodeW = (nN + 3) / 4;   // 1 wave/node, 4 waves/block

    // ---- CSR build + dinv ----
    hipMemsetAsync(cur, 0, (size_t)nN * sizeof(int), stream);
    deg_count_k<<<gEdgeT, thr, 0, stream>>>(edst, nE, cur);
    dinv_k<<<gNodeT, thr, 0, stream>>>(cur, nN, dinv);
    scan_k<<<1, 1024, 0, stream>>>(cur, nN, offs);
    hipMemcpyAsync(cur, offs, (size_t)nN * sizeof(int), hipMemcpyDeviceToDevice, stream);
    fill_k<<<gEdgeT, thr, 0, stream>>>(esrc, edst, nE, cur, elist);

    // ---- branch 1 ----
    mm64_k<1><<<1024, thr, 0, stream>>>(x, W1, We, dinv, A, B, nN);
    agg_combine_k<0><<<gNodeW, thr, 0, stream>>>(offs, elist, A, b1, B, be, dinv, H1, nN);
    mm64_k<0><<<1024, thr, 0, stream>>>(H1, W2, nullptr, dinv, A, nullptr, nN);
    agg_combine_k<1><<<gNodeW, thr, 0, stream>>>(offs, elist, A, b2, H1, nullptr, dinv, H2, nN);

    // ---- branch 2 ----
    mm64_k<1><<<1024, thr, 0, stream>>>(x_SC, W1s, Wes, dinv, A, B, nN);
    agg_combine_k<0><<<gNodeW, thr, 0, stream>>>(offs, elist, A, b1s, B, bes, dinv, H1, nN);
    mm64_k<0><<<1024, thr, 0, stream>>>(H1, W2s, nullptr, dinv, A, nullptr, nN);
    agg_combine_k<1><<<gNodeW, thr, 0, stream>>>(offs, elist, A, b2s, H1, nullptr, dinv, B, nN);

    // ---- pool + final projection (fused, atomic-free) ----
    pool_final_k<<<nG, thr, 0, stream>>>(H2, B, batch, nN, Wf, bf, (float*)d_out);
}